// Round 1
// baseline (69.461 us; speedup 1.0000x reference)
//
#include <hip/hip_runtime.h>

// out[b,t] = -sum_{i=0}^{15} lpc[b, t/160, i] * x[b, t-i],  x[<0] = 0
// B=1024, T=2400, N=16, F=160. All float32.
//
// One thread -> 4 consecutive outputs (one float4 store). F=160 is divisible
// by 4, so the 4 outputs share one lpc row. x window x[t-16 .. t+3] is 5
// aligned float4 loads (xrow is 16B-aligned since T*4=9600 bytes is a
// multiple of 16, and t-16 is a multiple of 4).

__global__ __launch_bounds__(256) void lpc_pred_kernel(
    const float* __restrict__ xt,   // [B, T]
    const float* __restrict__ lpc,  // [B, T/F, N]
    float* __restrict__ out)        // [B, T]
{
    constexpr int T = 2400;
    constexpr int N = 16;
    constexpr int F = 160;
    constexpr int FRAMES = T / F;   // 15
    constexpr int CHUNK = 1024;     // outputs per block (256 thr * 4)

    const int b = blockIdx.y;
    const int t = blockIdx.x * CHUNK + threadIdx.x * 4;
    if (t >= T) return;

    const float* __restrict__ xrow = xt + (size_t)b * T;
    const float* __restrict__ crow = lpc + ((size_t)b * FRAMES + (t / F)) * N;

    // 16 coefficients: 4 aligned float4 loads (crow is 64B-aligned).
    float cc[16];
    {
        const float4* cp = (const float4*)crow;
        #pragma unroll
        for (int k = 0; k < 4; ++k) {
            float4 v = cp[k];
            cc[4 * k + 0] = v.x; cc[4 * k + 1] = v.y;
            cc[4 * k + 2] = v.z; cc[4 * k + 3] = v.w;
        }
    }

    // xv[j] = x[t - 16 + j], j in [0, 20)
    float xv[20];
    if (t >= 16) {
        const float4* xp = (const float4*)(xrow + t - 16);
        #pragma unroll
        for (int k = 0; k < 5; ++k) {
            float4 v = xp[k];
            xv[4 * k + 0] = v.x; xv[4 * k + 1] = v.y;
            xv[4 * k + 2] = v.z; xv[4 * k + 3] = v.w;
        }
    } else {
        // only the first 4 threads of each row hit this (zero-pad region)
        #pragma unroll
        for (int j = 0; j < 20; ++j) {
            int g = t - 16 + j;
            xv[j] = (g >= 0) ? xrow[g] : 0.0f;
        }
    }

    // acc[d] = -sum_i cc[i] * x[t + d - i]; x[t+d-i] = xv[16 + d - i]
    float acc[4];
    #pragma unroll
    for (int d = 0; d < 4; ++d) {
        float s = 0.0f;
        #pragma unroll
        for (int i = 0; i < N; ++i) {
            s += cc[i] * xv[16 + d - i];
        }
        acc[d] = -s;
    }

    // T divisible by 4 and t % 4 == 0, so t+3 <= T-1 whenever t < T.
    *(float4*)(out + (size_t)b * T + t) = make_float4(acc[0], acc[1], acc[2], acc[3]);
}

extern "C" void kernel_launch(void* const* d_in, const int* in_sizes, int n_in,
                              void* d_out, int out_size, void* d_ws, size_t ws_size,
                              hipStream_t stream) {
    const float* xt  = (const float*)d_in[0];
    const float* lpc = (const float*)d_in[1];
    float* out = (float*)d_out;

    constexpr int B = 1024;
    constexpr int T = 2400;
    constexpr int CHUNK = 1024;

    dim3 grid((T + CHUNK - 1) / CHUNK, B);  // (3, 1024)
    dim3 block(256);
    lpc_pred_kernel<<<grid, block, 0, stream>>>(xt, lpc, out);
}

// Round 2
// 67.631 us; speedup vs baseline: 1.0271x; 1.0271x over previous
//
#include <hip/hip_runtime.h>

// out[b,t] = -sum_{i=0}^{15} lpc[b, t/160, i] * x[b, t-i],  x[<0] = 0
// B=1024, T=2400, N=16, F=160. All float32.
//
// One thread -> 8 consecutive outputs (two float4 stores). F=160 divisible
// by 8, so all 8 outputs share one lpc row. x window x[t-16 .. t+7] is 6
// aligned float4 loads. 1D grid: exactly B * (T/8) threads, no tail.

__global__ __launch_bounds__(256) void lpc_pred_kernel(
    const float* __restrict__ xt,   // [B, T]
    const float* __restrict__ lpc,  // [B, T/F, N]
    float* __restrict__ out)        // [B, T]
{
    constexpr int T = 2400;
    constexpr int N = 16;
    constexpr int F = 160;
    constexpr int FRAMES = T / F;   // 15
    constexpr int OPT = 8;          // outputs per thread
    constexpr int GPR = T / OPT;    // 300 groups per row

    const int tid = blockIdx.x * 256 + threadIdx.x;   // exactly B*GPR threads
    const int b = tid / GPR;
    const int j = tid - b * GPR;
    const int t = j * OPT;

    const float* __restrict__ xrow = xt + (size_t)b * T;
    const float* __restrict__ crow = lpc + ((size_t)b * FRAMES + (t / F)) * N;

    // 16 coefficients: 4 aligned float4 loads (crow is 64B-aligned).
    float cc[16];
    {
        const float4* cp = (const float4*)crow;
        #pragma unroll
        for (int k = 0; k < 4; ++k) {
            float4 v = cp[k];
            cc[4 * k + 0] = v.x; cc[4 * k + 1] = v.y;
            cc[4 * k + 2] = v.z; cc[4 * k + 3] = v.w;
        }
    }

    // xv[m] = x[t - 16 + m], m in [0, 24)
    float xv[24];
    if (t >= 16) {
        const float4* xp = (const float4*)(xrow + t - 16);
        #pragma unroll
        for (int k = 0; k < 6; ++k) {
            float4 v = xp[k];
            xv[4 * k + 0] = v.x; xv[4 * k + 1] = v.y;
            xv[4 * k + 2] = v.z; xv[4 * k + 3] = v.w;
        }
    } else {
        // only j in {0,1} per row hits this (zero-pad region)
        #pragma unroll
        for (int m = 0; m < 24; ++m) {
            int g = t - 16 + m;
            xv[m] = (g >= 0) ? xrow[g] : 0.0f;
        }
    }

    // acc[d] = -sum_i cc[i] * x[t + d - i]; x[t+d-i] = xv[16 + d - i]
    float acc[8];
    #pragma unroll
    for (int d = 0; d < OPT; ++d) {
        float s = 0.0f;
        #pragma unroll
        for (int i = 0; i < N; ++i) {
            s += cc[i] * xv[16 + d - i];
        }
        acc[d] = -s;
    }

    float* orow = out + (size_t)b * T + t;
    *(float4*)(orow + 0) = make_float4(acc[0], acc[1], acc[2], acc[3]);
    *(float4*)(orow + 4) = make_float4(acc[4], acc[5], acc[6], acc[7]);
}

extern "C" void kernel_launch(void* const* d_in, const int* in_sizes, int n_in,
                              void* d_out, int out_size, void* d_ws, size_t ws_size,
                              hipStream_t stream) {
    const float* xt  = (const float*)d_in[0];
    const float* lpc = (const float*)d_in[1];
    float* out = (float*)d_out;

    constexpr int B = 1024;
    constexpr int T = 2400;
    constexpr int OPT = 8;
    constexpr int THREADS = B * (T / OPT);  // 307200

    dim3 grid(THREADS / 256);  // 1200 blocks, exact
    dim3 block(256);
    lpc_pred_kernel<<<grid, block, 0, stream>>>(xt, lpc, out);
}